// Round 1
// baseline (361.034 us; speedup 1.0000x reference)
//
#include <hip/hip_runtime.h>

// VectorQuantizer: input (16,64,64,64) f32 channel-first, codebook (1024,64) f32.
// out = [quantized (16,64,64,64) f32 | indices (16,64,64) as f32], 4259840 elems.
//
// Round 0 baseline: thread-per-token fp32 VALU. score = e_sq[k] - 2*dot(x,c_k)
// (x_sq constant per token, dropped). First-index tie-break via strict <.

constexpr int D        = 64;
constexpr int K        = 1024;
constexpr int HW       = 4096;            // 64*64 spatial
constexpr int DHW      = D * HW;          // 262144
constexpr int N_TOK    = 65536;           // 16 * 4096
constexpr int OUT_ELEMS = 16 * DHW;       // 4194304 quantized floats

__global__ __launch_bounds__(256, 4) void vq_main(
    const float* __restrict__ input,
    const float* __restrict__ codebook,
    float* __restrict__ out)
{
    __shared__ float s_esq[K];
    const int tid = threadIdx.x;

    // Per-block e_sq precompute into LDS (256 threads x 4 codewords, trivial cost).
    #pragma unroll
    for (int i = 0; i < K / 256; ++i) {
        const int k = i * 256 + tid;
        const float4* c4 = (const float4*)(codebook + k * D);
        float a0 = 0.f, a1 = 0.f, a2 = 0.f, a3 = 0.f;
        #pragma unroll
        for (int j = 0; j < 16; ++j) {
            const float4 c = c4[j];
            a0 = fmaf(c.x, c.x, a0);
            a1 = fmaf(c.y, c.y, a1);
            a2 = fmaf(c.z, c.z, a2);
            a3 = fmaf(c.w, c.w, a3);
        }
        s_esq[k] = (a0 + a1) + (a2 + a3);
    }
    __syncthreads();

    const int t  = blockIdx.x * 256 + tid;
    const int b  = t >> 12;      // token / 4096
    const int hw = t & 4095;

    // Coalesced token load: lane i reads input[b, d, hw=i-contiguous]
    const float* xp = input + (size_t)b * DHW + hw;
    float x[D];
    #pragma unroll
    for (int d = 0; d < D; ++d) x[d] = xp[(size_t)d * HW];

    float best = 3.402823466e+38f;
    int   bidx = 0;

    #pragma unroll 1
    for (int k = 0; k < K; ++k) {
        // k is wave-uniform -> codebook loads are uniform (scalar-load friendly)
        const float4* c4 = (const float4*)(codebook + k * D);
        float a0 = 0.f, a1 = 0.f, a2 = 0.f, a3 = 0.f;
        #pragma unroll
        for (int j = 0; j < 16; ++j) {
            const float4 c = c4[j];
            a0 = fmaf(x[4 * j + 0], c.x, a0);
            a1 = fmaf(x[4 * j + 1], c.y, a1);
            a2 = fmaf(x[4 * j + 2], c.z, a2);
            a3 = fmaf(x[4 * j + 3], c.w, a3);
        }
        const float dot   = (a0 + a1) + (a2 + a3);
        const float score = fmaf(-2.0f, dot, s_esq[k]);
        if (score < best) { best = score; bidx = k; }   // strict < => first min
    }

    // Write quantized vector: coalesced per-channel stores (stride HW across d,
    // lane-contiguous within each d). Codebook gather is L1/L2-resident.
    float* op = out + (size_t)b * DHW + hw;
    const float4* cq = (const float4*)(codebook + bidx * D);
    #pragma unroll
    for (int j = 0; j < 16; ++j) {
        const float4 c = cq[j];
        op[(size_t)(4 * j + 0) * HW] = c.x;
        op[(size_t)(4 * j + 1) * HW] = c.y;
        op[(size_t)(4 * j + 2) * HW] = c.z;
        op[(size_t)(4 * j + 3) * HW] = c.w;
    }

    // Indices chunk, stored as f32 (harness reads tuple buffer as f32).
    out[OUT_ELEMS + t] = (float)bidx;
}

extern "C" void kernel_launch(void* const* d_in, const int* in_sizes, int n_in,
                              void* d_out, int out_size, void* d_ws, size_t ws_size,
                              hipStream_t stream) {
    const float* input    = (const float*)d_in[0];
    const float* codebook = (const float*)d_in[1];
    float* out            = (float*)d_out;
    vq_main<<<N_TOK / 256, 256, 0, stream>>>(input, codebook, out);
}

// Round 2
// 232.971 us; speedup vs baseline: 1.5497x; 1.5497x over previous
//
#include <hip/hip_runtime.h>

// VectorQuantizer: input (16,64,64,64) f32 channel-first, codebook (1024,64) f32.
// out = [quantized (16,64,64,64) f32 | indices (16,64,64) as f32].
//
// R1: TLP restructure. Block = 256 thr = 4 waves, handles 64 tokens.
// Wave w scans codewords [w*256, (w+1)*256) for all 64 tokens (lane = token).
// Grid = 1024 blocks -> 4 blocks/CU = 16 waves/CU (was 4). Codebook k-range is
// wave-uniform via readfirstlane -> scalar s_load broadcast, zero vector VMEM
// in the hot loop. 4-quarter LDS reduction, ascending q, strict < (first-index
// tie-break preserved). Per-k arithmetic identical to R0 (absmax was 0.0).

constexpr int D         = 64;
constexpr int K         = 1024;
constexpr int HW        = 4096;        // 64*64
constexpr int DHW       = D * HW;      // 262144
constexpr int OUT_ELEMS = 16 * DHW;    // quantized floats
constexpr int KQ        = K / 4;       // 256 codewords per wave

__global__ __launch_bounds__(256, 4) void vq_main(
    const float* __restrict__ input,
    const float* __restrict__ codebook,
    float* __restrict__ out)
{
    __shared__ float s_esq[K];
    __shared__ float s_best[4][64];
    __shared__ int   s_bidx[4][64];

    const int tid = threadIdx.x;

    // e_sq precompute (256 thr x 4 codewords)
    #pragma unroll
    for (int i = 0; i < 4; ++i) {
        const int k = i * 256 + tid;
        const float4* c4 = (const float4*)(codebook + k * D);
        float a0 = 0.f, a1 = 0.f, a2 = 0.f, a3 = 0.f;
        #pragma unroll
        for (int j = 0; j < 16; ++j) {
            const float4 c = c4[j];
            a0 = fmaf(c.x, c.x, a0);
            a1 = fmaf(c.y, c.y, a1);
            a2 = fmaf(c.z, c.z, a2);
            a3 = fmaf(c.w, c.w, a3);
        }
        s_esq[k] = (a0 + a1) + (a2 + a3);
    }
    __syncthreads();

    const int lane    = tid & 63;
    const int quarter = __builtin_amdgcn_readfirstlane(tid >> 6);  // wave-uniform
    const int tok     = blockIdx.x * 64 + lane;
    const int b       = tok >> 12;
    const int hw      = tok & 4095;

    // Token load: lane-contiguous hw -> coalesced 256B/wave per channel.
    // 16 float4 vars -> 64 VGPRs, register-resident.
    const float* xp = input + (size_t)b * DHW + hw;
    float4 xv[16];
    #pragma unroll
    for (int j = 0; j < 16; ++j) {
        xv[j].x = xp[(size_t)(4 * j + 0) * HW];
        xv[j].y = xp[(size_t)(4 * j + 1) * HW];
        xv[j].z = xp[(size_t)(4 * j + 2) * HW];
        xv[j].w = xp[(size_t)(4 * j + 3) * HW];
    }

    const int    k0 = quarter * KQ;
    const float* cb = codebook + (size_t)k0 * D;   // uniform base

    float best = 3.402823466e+38f;
    int   bidx = 0;

    #pragma unroll 2
    for (int kk = 0; kk < KQ; ++kk) {
        const float* c = cb + kk * D;              // uniform -> s_load
        float a0 = 0.f, a1 = 0.f, a2 = 0.f, a3 = 0.f;
        #pragma unroll
        for (int j = 0; j < 16; ++j) {
            a0 = fmaf(xv[j].x, c[4 * j + 0], a0);
            a1 = fmaf(xv[j].y, c[4 * j + 1], a1);
            a2 = fmaf(xv[j].z, c[4 * j + 2], a2);
            a3 = fmaf(xv[j].w, c[4 * j + 3], a3);
        }
        const float dot   = (a0 + a1) + (a2 + a3);
        const float score = fmaf(-2.0f, dot, s_esq[k0 + kk]);
        if (score < best) { best = score; bidx = kk; }  // strict < => first min
    }
    bidx += k0;

    s_best[quarter][lane] = best;
    s_bidx[quarter][lane] = bidx;
    __syncthreads();

    if (tid < 64) {
        float bb = s_best[0][lane];
        int   bi = s_bidx[0][lane];
        #pragma unroll
        for (int q = 1; q < 4; ++q) {
            const float v  = s_best[q][lane];
            const int   id = s_bidx[q][lane];
            if (v < bb) { bb = v; bi = id; }   // ascending q, strict < => first min
        }

        // Quantized write: coalesced per-channel stores; codebook gather L2-hit.
        float*        op = out + (size_t)b * DHW + hw;
        const float4* cq = (const float4*)(codebook + bi * D);
        #pragma unroll
        for (int j = 0; j < 16; ++j) {
            const float4 c = cq[j];
            op[(size_t)(4 * j + 0) * HW] = c.x;
            op[(size_t)(4 * j + 1) * HW] = c.y;
            op[(size_t)(4 * j + 2) * HW] = c.z;
            op[(size_t)(4 * j + 3) * HW] = c.w;
        }
        out[OUT_ELEMS + tok] = (float)bi;
    }
}

extern "C" void kernel_launch(void* const* d_in, const int* in_sizes, int n_in,
                              void* d_out, int out_size, void* d_ws, size_t ws_size,
                              hipStream_t stream) {
    const float* input    = (const float*)d_in[0];
    const float* codebook = (const float*)d_in[1];
    float* out            = (float*)d_out;
    vq_main<<<1024, 256, 0, stream>>>(input, codebook, out);
}

// Round 3
// 145.948 us; speedup vs baseline: 2.4737x; 1.5963x over previous
//
#include <hip/hip_runtime.h>

// VectorQuantizer: input (16,64,64,64) f32 channel-first, codebook (1024,64) f32.
// out = [quantized (16,64,64,64) f32 | indices (16,64,64) as f32].
//
// R2: MFMA f16 approximate scan + exact fp32 rescan of near-ties.
//  - prep kernel: codebook -> f16 B-fragments (MFMA-swizzled) + e_sq (fp32).
//  - scan kernel: 1024 blocks x 4 waves; wave = 64 tokens x 256 codewords
//    via mfma_f32_32x32x16_f16 (2 M-tiles x 4 K-chunks per cw-tile).
//    score = e_sq - 2*dot; per-entry running (min, 2nd-min) of packed
//    (score & ~7 | tile) floats; v_med3 maintains 2nd-min in 1 instr.
//  - tokens with top2 gap < EPS (=0.05, ~5 sigma of f16 noise) get exact
//    fp32 full-K rescan (wave-parallel, ~1% of tokens) => argmin matches
//    the fp32 reference exactly, incl. first-index tie-break.

typedef _Float16 v8h  __attribute__((ext_vector_type(8)));
typedef float    v16f __attribute__((ext_vector_type(16)));

constexpr int   D         = 64;
constexpr int   K         = 1024;
constexpr int   HW        = 4096;
constexpr int   DHW       = D * HW;
constexpr int   OUT_ELEMS = 16 * DHW;
constexpr float EPS       = 0.05f;

// ---------------- prep: codebook -> f16 fragments + e_sq ----------------
// CH fragment layout: frag index g = (T*4 + kc)*64 + lane, 8 f16 each:
//   CH[g][j] = C[cw = T*32 + (lane&31)][d = kc*16 + (lane>>5)*8 + j]
__global__ __launch_bounds__(256) void vq_prep(
    const float* __restrict__ cb, _Float16* __restrict__ CH, float* __restrict__ esq)
{
    if (blockIdx.x < 32) {
        const int gid  = blockIdx.x * 256 + threadIdx.x;   // [0, 8192)
        const int lane = gid & 63;
        const int kcT  = gid >> 6;
        const int kc   = kcT & 3;
        const int T    = kcT >> 2;
        const int cw   = T * 32 + (lane & 31);
        const int d0   = kc * 16 + ((lane >> 5) << 3);
        const float* src = cb + cw * D + d0;
        v8h h;
        #pragma unroll
        for (int j = 0; j < 8; ++j) h[j] = (_Float16)src[j];
        *(v8h*)(CH + (size_t)gid * 8) = h;
    } else {
        const int t = threadIdx.x;
        #pragma unroll
        for (int i = 0; i < 4; ++i) {
            const int cw = i * 256 + t;
            const float4* c4 = (const float4*)(cb + cw * D);
            float a0 = 0.f, a1 = 0.f, a2 = 0.f, a3 = 0.f;
            #pragma unroll
            for (int j = 0; j < 16; ++j) {
                const float4 c = c4[j];
                a0 = fmaf(c.x, c.x, a0);
                a1 = fmaf(c.y, c.y, a1);
                a2 = fmaf(c.z, c.z, a2);
                a3 = fmaf(c.w, c.w, a3);
            }
            esq[cw] = (a0 + a1) + (a2 + a3);
        }
    }
}

// ---------------- main scan ----------------
__global__ __launch_bounds__(256, 3) void vq_scan(
    const float* __restrict__ input,
    const float* __restrict__ codebook,
    const _Float16* __restrict__ CH,
    const float* __restrict__ esq,
    float* __restrict__ out)
{
    __shared__ float    s_min[4][64][36];  // [q][token][col] packed scores (36 = pad)
    __shared__ float    s_pv[4][64];       // per-(q,token) best
    __shared__ int      s_pk[4][64];       // per-(q,token) best cw
    __shared__ float    s_p2[4][64];       // per-(q,token) second best
    __shared__ int      s_idx[64];
    __shared__ unsigned s_mask[2];
    __shared__ float    s_x[4][64];        // rescan token staging, per wave

    const int tid  = threadIdx.x;
    const int lane = tid & 63;
    const int q    = __builtin_amdgcn_readfirstlane(tid >> 6);  // k-quarter
    const int tok0 = blockIdx.x * 64;
    const int b    = tok0 >> 12;
    const int hw0  = tok0 & 4095;
    const int l31  = lane & 31;
    const int lh   = lane >> 5;

    if (tid < 2) s_mask[tid] = 0u;

    // ---- A fragments: 2 M-tiles x 4 K-chunks, 8 f16/lane each ----
    // A[m = lane&31][k = (lane>>5)*8 + j] per mfma_32x32x16 (m120-analog layout)
    v8h a[2][4];
    {
        const float* xbase = input + (size_t)b * DHW + hw0;
        #pragma unroll
        for (int mt = 0; mt < 2; ++mt) {
            const int hwo = mt * 32 + l31;
            #pragma unroll
            for (int kc = 0; kc < 4; ++kc) {
                const int d0 = kc * 16 + lh * 8;
                #pragma unroll
                for (int j = 0; j < 8; ++j)
                    a[mt][kc][j] = (_Float16)xbase[(size_t)(d0 + j) * HW + hwo];
            }
        }
    }

    // e_sq per (col) per tile, hoisted
    float e[8];
    #pragma unroll
    for (int t = 0; t < 8; ++t) e[t] = esq[q * 256 + t * 32 + l31];

    const v8h* Bl = (const v8h*)CH + (size_t)(q * 8) * 4 * 64 + lane;

    const float INF = __builtin_huge_valf();
    float bv[2][16], b2[2][16];
    #pragma unroll
    for (int mt = 0; mt < 2; ++mt)
        #pragma unroll
        for (int r = 0; r < 16; ++r) { bv[mt][r] = INF; b2[mt][r] = INF; }

    #pragma unroll 2
    for (int t = 0; t < 8; ++t) {
        v8h bf[4];
        #pragma unroll
        for (int kc = 0; kc < 4; ++kc) bf[kc] = Bl[(t * 4 + kc) * 64];

        v16f acc0 = {0,0,0,0,0,0,0,0,0,0,0,0,0,0,0,0};
        v16f acc1 = {0,0,0,0,0,0,0,0,0,0,0,0,0,0,0,0};
        #pragma unroll
        for (int kc = 0; kc < 4; ++kc) {
            acc0 = __builtin_amdgcn_mfma_f32_32x32x16_f16(a[0][kc], bf[kc], acc0, 0, 0, 0);
            acc1 = __builtin_amdgcn_mfma_f32_32x32x16_f16(a[1][kc], bf[kc], acc1, 0, 0, 0);
        }

        // score fixup + pack tile into low 3 mantissa bits + top-2 track
        #pragma unroll
        for (int r = 0; r < 16; ++r) {
            float s0 = fmaf(-2.0f, acc0[r], e[t]);
            s0 = __uint_as_float((__float_as_uint(s0) & ~7u) | (unsigned)t);
            b2[0][r] = __builtin_amdgcn_fmed3f(s0, bv[0][r], b2[0][r]);
            bv[0][r] = fminf(bv[0][r], s0);
            float s1 = fmaf(-2.0f, acc1[r], e[t]);
            s1 = __uint_as_float((__float_as_uint(s1) & ~7u) | (unsigned)t);
            b2[1][r] = __builtin_amdgcn_fmed3f(s1, bv[1][r], b2[1][r]);
            bv[1][r] = fminf(bv[1][r], s1);
        }
    }

    // ---- phase 1: write per-entry bests; per-(q,token) col scan ----
    #pragma unroll
    for (int mt = 0; mt < 2; ++mt)
        #pragma unroll
        for (int r = 0; r < 16; ++r) {
            const int row = (r & 3) + 8 * (r >> 2) + 4 * lh + 32 * mt;
            s_min[q][row][l31] = bv[mt][r];
        }
    __syncthreads();

    // thread -> (q2 = tid>>6, token = tid&63): scan 32 cols
    const int token = tid & 63;
    float v1 = INF, v2c = INF; int c1 = 0;
    {
        const float* rowp = s_min[q][token];
        #pragma unroll
        for (int c = 0; c < 32; ++c) {
            const float v = rowp[c];
            if (v < v1) { v2c = v1; v1 = v; c1 = c; }
            else if (v < v2c) { v2c = v; }
        }
    }
    __syncthreads();

    // ---- phase 2: overwrite with per-entry second-bests; fetch winner cell's b2 ----
    #pragma unroll
    for (int mt = 0; mt < 2; ++mt)
        #pragma unroll
        for (int r = 0; r < 16; ++r) {
            const int row = (r & 3) + 8 * (r >> 2) + 4 * lh + 32 * mt;
            s_min[q][row][l31] = b2[mt][r];
        }
    __syncthreads();

    {
        const float cell2 = s_min[q][token][c1];
        const int   tile  = (int)(__float_as_uint(v1) & 7u);
        s_pv[q][token] = v1;
        s_pk[q][token] = q * 256 + tile * 32 + c1;
        s_p2[q][token] = fminf(v2c, cell2);
    }
    __syncthreads();

    // ---- merge 4 quarters per token (threads 0..63) ----
    if (tid < 64) {
        float B1 = INF, B2 = INF; int CW = 0;
        #pragma unroll
        for (int qq = 0; qq < 4; ++qq) {
            const float pv = s_pv[qq][tid];
            const float p2 = s_p2[qq][tid];
            const int   pk = s_pk[qq][tid];
            if (pv < B1) { B2 = fminf(B1, p2); B1 = pv; CW = pk; }
            else         { B2 = fminf(B2, pv); }
        }
        s_idx[tid] = CW;
        if (B2 - B1 < EPS)
            atomicOr(&s_mask[tid >> 5], 1u << (tid & 31));
    }
    __syncthreads();

    // ---- exact fp32 rescan for uncertain tokens (rare) ----
    const unsigned m0 = s_mask[0], m1 = s_mask[1];
    int ui = 0;
    for (int h = 0; h < 2; ++h) {
        unsigned m = (h == 0) ? m0 : m1;
        while (m) {
            const int bit = __ffs(m) - 1;
            m &= m - 1;
            const int tl = h * 32 + bit;
            if ((ui & 3) == q) {
                // stage x
                s_x[q][lane] = input[(size_t)b * DHW + (size_t)lane * HW + (hw0 + tl)];
                const float4* xs4 = (const float4*)s_x[q];
                float bestv = INF; int bestk = K;
                for (int rr = 0; rr < 16; ++rr) {
                    const int k = lane + rr * 64;
                    const float4* c4 = (const float4*)(codebook + (size_t)k * D);
                    float a0 = 0.f, a1 = 0.f, a2 = 0.f, a3 = 0.f;
                    #pragma unroll
                    for (int j = 0; j < 16; ++j) {
                        const float4 c = c4[j];
                        const float4 xv = xs4[j];
                        a0 = fmaf(xv.x, c.x, a0);
                        a1 = fmaf(xv.y, c.y, a1);
                        a2 = fmaf(xv.z, c.z, a2);
                        a3 = fmaf(xv.w, c.w, a3);
                    }
                    const float s = fmaf(-2.0f, (a0 + a1) + (a2 + a3), esq[k]);
                    if (s < bestv) { bestv = s; bestk = k; }  // k ascends within lane
                }
                #pragma unroll
                for (int off = 32; off >= 1; off >>= 1) {
                    const float ov = __shfl_xor(bestv, off, 64);
                    const int   ok = __shfl_xor(bestk, off, 64);
                    if (ov < bestv || (ov == bestv && ok < bestk)) { bestv = ov; bestk = ok; }
                }
                if (lane == 0) s_idx[tl] = bestk;
            }
            ++ui;
        }
    }
    __syncthreads();

    // ---- epilogue: quantized write (coalesced per-channel) + indices ----
    {
        const int tok = tid & 63;
        const int dq  = tid >> 6;
        const int idx = s_idx[tok];
        const int hw  = hw0 + tok;
        const float4* c4 = (const float4*)(codebook + (size_t)idx * D + dq * 16);
        float* op = out + (size_t)b * DHW + (size_t)dq * 16 * HW + hw;
        #pragma unroll
        for (int j = 0; j < 4; ++j) {
            const float4 c = c4[j];
            op[(size_t)(4 * j + 0) * HW] = c.x;
            op[(size_t)(4 * j + 1) * HW] = c.y;
            op[(size_t)(4 * j + 2) * HW] = c.z;
            op[(size_t)(4 * j + 3) * HW] = c.w;
        }
        if (tid < 64) out[OUT_ELEMS + tok0 + tid] = (float)s_idx[tid];
    }
}

extern "C" void kernel_launch(void* const* d_in, const int* in_sizes, int n_in,
                              void* d_out, int out_size, void* d_ws, size_t ws_size,
                              hipStream_t stream) {
    const float* input    = (const float*)d_in[0];
    const float* codebook = (const float*)d_in[1];
    float* out            = (float*)d_out;

    _Float16* CH  = (_Float16*)d_ws;                       // 131072 B
    float*    esq = (float*)((char*)d_ws + 131072);        // 4096 B

    vq_prep<<<33, 256, 0, stream>>>(codebook, CH, esq);
    vq_scan<<<1024, 256, 0, stream>>>(input, codebook, CH, esq, out);
}